// Round 9
// baseline (174.039 us; speedup 1.0000x reference)
//
#include <hip/hip_runtime.h>
#include <hip/hip_fp16.h>

// dot_attention: out[b,n] = exp(diag*s - lse_n), s = (D/2)^-0.5 = 1/16.
// B=4, N=4096, D=512. Inputs fp32, output fp32.
// No fp32 MFMA on CDNA4 -> fp16 convert + mfma_f32_16x16x32_f16.
//
// R9 = R8 (128-thr blocks, 4 blocks/CU, 16-row dbuf tiles) + explicit
// s_waitcnt vmcnt(0) before every __syncthreads in the K-loop.
// R8 failed the determinism tripwire: graph replay validated but a fresh
// launch diverged -> timing race. The dbuf handshake requires vmcnt(0)
// (global_load_lds DMA drain) before s_barrier; that wait is a compiler
// inference that evidently disappeared with the R8 code shape. Explicit
// fence = idempotent if already emitted, correctness-restoring if not.

typedef _Float16 f16x8 __attribute__((ext_vector_type(8)));  // MFMA A/B frag (4 VGPR)
typedef float    f32x4 __attribute__((ext_vector_type(4)));  // MFMA C/D frag

#define NB 4
#define NN 4096
#define ND 512
#define SCALE 0.0625f
#define LOG2E 1.4426950408889634f
#define NROWS (NB * NN)            // 16384
#define FRAG_B 1024                // bytes per packed fragment
#define GRP_B  16384               // bytes per 16-row group (16 frags) = tile
#define CPITCH 520                 // convert LDS row pitch (halfwords) = 1040 B

__device__ __forceinline__ void gld16(const void* g, void* l) {
    __builtin_amdgcn_global_load_lds(
        (const __attribute__((address_space(1))) unsigned int*)g,
        (__attribute__((address_space(3))) unsigned int*)l, 16, 0, 0);
}

// Explicit DMA drain: __syncthreads' correctness here depends on all
// outstanding global_load_lds being complete; do not rely on the compiler
// inferring it (R8 tripwire).
__device__ __forceinline__ void vmfence() {
    asm volatile("s_waitcnt vmcnt(0)" ::: "memory");
}

__device__ __forceinline__ f16x8 cvt8(float4 a, float4 b) {
    f16x8 r;
    r[0] = (_Float16)a.x; r[1] = (_Float16)a.y; r[2] = (_Float16)a.z; r[3] = (_Float16)a.w;
    r[4] = (_Float16)b.x; r[5] = (_Float16)b.y; r[6] = (_Float16)b.z; r[7] = (_Float16)b.w;
    return r;
}

__device__ __forceinline__ f16x8 cvt8s(float4 a, float4 b, float s) {
    f16x8 r;
    r[0] = (_Float16)(a.x * s); r[1] = (_Float16)(a.y * s);
    r[2] = (_Float16)(a.z * s); r[3] = (_Float16)(a.w * s);
    r[4] = (_Float16)(b.x * s); r[5] = (_Float16)(b.y * s);
    r[6] = (_Float16)(b.z * s); r[7] = (_Float16)(b.w * s);
    return r;
}

__device__ __forceinline__ float sel4(const f32x4& a, int j) {
    return (j == 0) ? a[0] : (j == 1) ? a[1] : (j == 2) ? a[2] : a[3];
}

// ---- kernel 1: kv fp32 -> fp16, packed in B-frag order via LDS transpose.
// One 16-row group per block (1024 blocks). frag(g,kt) byte lane*16 =
// kv[g*16 + (lane&15)][kt*32 + (lane>>4)*8 ..+8) as fp16.
__launch_bounds__(256)
__global__ void convert_kernel(const float* __restrict__ kv,
                               _Float16* __restrict__ kvp) {
    __shared__ _Float16 s[16 * CPITCH];
    const int g    = blockIdx.x;
    const int tid  = threadIdx.x;
    const int wid  = tid >> 6;
    const int lane = tid & 63;
    const int l15  = lane & 15;
    const int quad = lane >> 4;

    #pragma unroll
    for (int i = 0; i < 4; ++i) {
        const int r = wid * 4 + i;
        const float* src = kv + ((size_t)g * 16 + r) * ND + lane * 8;
        float4 a = *(const float4*)src;
        float4 b = *(const float4*)(src + 4);
        *(f16x8*)(s + r * CPITCH + lane * 8) = cvt8(a, b);
    }
    __syncthreads();

    _Float16* dst = kvp + (size_t)g * 8192 + lane * 8;
    #pragma unroll
    for (int p = 0; p < 4; ++p) {
        const int kt = wid * 4 + p;
        f16x8 v = *(const f16x8*)(s + l15 * CPITCH + kt * 32 + quad * 8);
        *(f16x8*)(dst + kt * 512) = v;
    }
}

// ---- kernel 2: per-row sum of exp(score) over a 1024-column split + diag.
// grid (16: b*4+cs, 64: rowblock) = 1024 blocks, 128 threads = 2 waves,
// 4 blocks/CU (2x16KB LDS dbuf), 8 waves/CU from 4 independent blocks.
// Wave: 32 q-rows (Af 128 regs). Per iter: one 16-row packed group via LDS
// DMA dbuf; 16 b128 reads, 32 MFMA.
__launch_bounds__(128, 2)
__global__ void lse_partial_kernel(const float* __restrict__ q,
                                   const _Float16* __restrict__ kvp,
                                   float* __restrict__ partial,
                                   float* __restrict__ diagsc) {
    __shared__ char sbuf[2][GRP_B];

    const int bc = blockIdx.x;          // b*4 + cs (fastest -> spread over XCDs)
    const int b  = bc >> 2;
    const int cs = bc & 3;
    const int rb = blockIdx.y;
    const int tid  = threadIdx.x;
    const int wid  = tid >> 6;          // 0..1
    const int lane = tid & 63;
    const int l15  = lane & 15;
    const int quad = lane >> 4;

    const int row0 = rb * 64 + wid * 32;     // wave's first q-row (in batch)
    // tiles (16 cols each) whose columns coincide with this wave's q-rows
    const bool aligned = ((row0 >> 10) == cs);
    const int itd0 = aligned ? ((row0 & 1023) >> 4) : -1;   // m=0 frag rows
    const int itd1 = aligned ? itd0 + 1 : -1;               // m=1 frag rows

    // ---- A fragments: q fp32 -> fp16 scaled by s*log2e (exp2 path).
    f16x8 Af[2][16];
    #pragma unroll
    for (int m = 0; m < 2; ++m) {
        const float* qrow = q + ((size_t)(b * NN + row0 + m * 16 + l15)) * ND + quad * 8;
        #pragma unroll
        for (int k = 0; k < 16; ++k) {
            float4 u0 = *(const float4*)(qrow + k * 32);
            float4 u1 = *(const float4*)(qrow + k * 32 + 4);
            Af[m][k] = cvt8s(u0, u1, SCALE * LOG2E);
        }
    }

    float lacc[2][4];
    #pragma unroll
    for (int m = 0; m < 2; ++m)
        #pragma unroll
        for (int j = 0; j < 4; ++j)
            lacc[m][j] = 0.f;

    // packed base for this (b,cs): 64 groups (= 64 tiles of 16 columns)
    const char* pb  = (const char*)kvp + ((size_t)(b * 256 + cs * 64)) * GRP_B;
    const char* ssb = pb + (size_t)lane * 16;

    // stage 16-frag tile `it_` into sbuf[buf_]: 8 frag-DMAs per wave
    #define STAGE(it_, buf_)                                                  \
        do {                                                                  \
            const char* sp_ = ssb + (size_t)(it_) * GRP_B;                    \
            char* lb_ = sbuf[buf_];                                           \
            _Pragma("unroll")                                                 \
            for (int p_ = 0; p_ < 8; ++p_) {                                  \
                int f_ = wid * 8 + p_;                                        \
                gld16(sp_ + f_ * FRAG_B, lb_ + f_ * FRAG_B);                  \
            }                                                                 \
        } while (0)

    STAGE(0, 0);
    int buf = 0;

    for (int it = 0; it < 64; ++it) {
        vmfence();                            // drain this wave's DMA
        __syncthreads();                      // all waves' tile-`it` DMA visible
        if (it + 1 < 64) STAGE(it + 1, buf ^ 1);

        const char* lb = sbuf[buf] + (size_t)lane * 16;
        f32x4 acc0 = (f32x4){0.f, 0.f, 0.f, 0.f};
        f32x4 acc1 = (f32x4){0.f, 0.f, 0.f, 0.f};

        #pragma unroll
        for (int kt = 0; kt < 16; ++kt) {
            f16x8 b0 = *(const f16x8*)(lb + kt * FRAG_B);
            acc0 = __builtin_amdgcn_mfma_f32_16x16x32_f16(Af[0][kt], b0, acc0, 0, 0, 0);
            acc1 = __builtin_amdgcn_mfma_f32_16x16x32_f16(Af[1][kt], b0, acc1, 0, 0, 0);
        }

        // diag: C/D row = quad*4+j, col = l15; diagonal lanes l15==quad*4+j.
        if (it == itd0 && (l15 >> 2) == quad)
            diagsc[b * NN + row0 + l15] = sel4(acc0, l15 & 3);        // m=0 rows
        if (it == itd1 && (l15 >> 2) == quad)
            diagsc[b * NN + row0 + 16 + l15] = sel4(acc1, l15 & 3);   // m=1 rows

        // acc = score*log2e -> exp(score) = exp2(acc)
        #pragma unroll
        for (int j = 0; j < 4; ++j) {
            lacc[0][j] += __builtin_amdgcn_exp2f(acc0[j]);
            lacc[1][j] += __builtin_amdgcn_exp2f(acc1[j]);
        }

        buf ^= 1;
    }

    // reduce over the 16 columns held across l15 lanes
    #pragma unroll
    for (int m = 0; m < 2; ++m)
        #pragma unroll
        for (int j = 0; j < 4; ++j) {
            float v = lacc[m][j];
            v += __shfl_xor(v, 1, 64);
            v += __shfl_xor(v, 2, 64);
            v += __shfl_xor(v, 4, 64);
            v += __shfl_xor(v, 8, 64);
            if (l15 == 0)
                partial[(size_t)cs * NROWS + b * NN + row0 + m * 16 + quad * 4 + j] = v;
        }
}

// ---- kernel 3: out = exp2(diag_scaled) / sum_cs partial
__launch_bounds__(256)
__global__ void finalize_kernel(const float* __restrict__ partial,
                                const float* __restrict__ diagsc,
                                float* __restrict__ out) {
    const int idx = blockIdx.x * 256 + threadIdx.x;
    float l = partial[idx] + partial[NROWS + idx] +
              partial[2 * NROWS + idx] + partial[3 * NROWS + idx];
    out[idx] = exp2f(diagsc[idx]) / l;
}

extern "C" void kernel_launch(void* const* d_in, const int* in_sizes, int n_in,
                              void* d_out, int out_size, void* d_ws, size_t ws_size,
                              hipStream_t stream) {
    const float* q  = (const float*)d_in[0];
    const float* kv = (const float*)d_in[1];
    float* out = (float*)d_out;

    // ws: kvp fp16 packed [16MB] | partial f32[4][16384] | diagsc f32[16384]
    _Float16* kvp   = (_Float16*)d_ws;
    float* partial  = (float*)((char*)d_ws + (size_t)NROWS * ND * 2);
    float* diagsc   = partial + 4 * NROWS;

    convert_kernel<<<1024, 256, 0, stream>>>(kv, kvp);
    lse_partial_kernel<<<dim3(16, 64), 128, 0, stream>>>(q, kvp, partial, diagsc);
    finalize_kernel<<<NROWS / 256, 256, 0, stream>>>(partial, diagsc, out);
}